// Round 10
// baseline (519.136 us; speedup 1.0000x reference)
//
#include <hip/hip_runtime.h>
#include <math.h>

#define NN 100000
#define NE 1600000
#define H 128
#define LH 384
#define GG 512
#define CC 10
#define EPSBN 1e-5f
#define BSH 9  // bucket shift: 512 nodes per bucket

typedef __attribute__((ext_vector_type(4))) float f32x4;
typedef __attribute__((ext_vector_type(2))) float f32x2;
typedef __attribute__((ext_vector_type(8))) short s16x8;
typedef __attribute__((ext_vector_type(4))) uint u32x4;
typedef unsigned long long u64;

__device__ inline ushort f2b(float f) {
    uint u = __float_as_uint(f);
    uint r = (u + 0x7FFFu + ((u >> 16) & 1u)) >> 16;
    return (ushort)r;
}
__device__ inline float b2f(ushort b) { return __uint_as_float(((uint)b) << 16); }
__device__ inline float blo(uint v) { return __uint_as_float(v << 16); }
__device__ inline float bhi(uint v) { return __uint_as_float(v & 0xFFFF0000u); }

// ---------------- fused: W transpose/convert + edge bucket histogram -------
// blocks [0,192): WT[mat][j][k] = bf16(W[mat][k][j])  (2 (mat,k) pairs/block)
// blocks [192,448): 256-block grid-stride histogram of dst buckets

__global__ void k_wt_bhist(const float* __restrict__ W1, const float* __restrict__ Wc,
                           ushort* __restrict__ WT,
                           const int* __restrict__ dst, int* __restrict__ bhist,
                           int e, int nbuck) {
    int t = threadIdx.x;
    if (blockIdx.x < 192) {
        int idx = blockIdx.x * 2 + (t >> 7);  // 0..383 = mat*128 + k
        int mat = idx >> 7;
        int k = idx & 127;
        int j = t & 127;
        const float* W = (mat == 0) ? W1 : Wc + (size_t)(mat - 1) * H * H;
        WT[(size_t)mat * H * H + j * H + k] = f2b(W[(size_t)k * H + j]);
        return;
    }
    __shared__ int lh[256];
    lh[t] = 0;
    __syncthreads();
    int hb = blockIdx.x - 192;
    for (int i = hb * 256 + t; i < e; i += 256 * 256)
        atomicAdd(&lh[dst[i] >> BSH], 1);
    __syncthreads();
    int v = lh[t];
    if (t < nbuck && v) atomicAdd(&bhist[t], v);
}

// block-aggregated scatter, LDS-staged: records binned into LDS by bucket,
// then streamed out in bucket order -> coalesced runs. Bucket bases are
// recomputed in-block from bhist (256-entry LDS scan); bcursor is zero-based.
// packed u32 record: (dst & 511) << 17 | src
__global__ void k_bin(const int* __restrict__ src, const int* __restrict__ dst,
                      const int* __restrict__ bhist, int* __restrict__ bcursor,
                      uint* __restrict__ ebuf, int e) {
    __shared__ int lh[256], gb[256], lbase[256], lcur[256], sh[256];
    __shared__ uint rec[4096];
    __shared__ unsigned char bkt[4096];
    int t = threadIdx.x;
    // bucket base = exclusive scan of bhist
    int hv = bhist[t];
    sh[t] = hv;
    __syncthreads();
    for (int off = 1; off < 256; off <<= 1) {
        int x = (t >= off) ? sh[t - off] : 0;
        __syncthreads();
        sh[t] += x;
        __syncthreads();
    }
    int rbb = sh[t] - hv;  // bbase[t]
    __syncthreads();
    int base = blockIdx.x * 4096;
    int lim = e - base; if (lim > 4096) lim = 4096;
    lh[t] = 0;
    __syncthreads();
    for (int i = t; i < lim; i += 256)
        atomicAdd(&lh[dst[base + i] >> BSH], 1);
    __syncthreads();
    int c = lh[t];
    if (c) gb[t] = rbb + atomicAdd(&bcursor[t], c);
    sh[t] = c;
    __syncthreads();
    for (int off = 1; off < 256; off <<= 1) {
        int x = (t >= off) ? sh[t - off] : 0;
        __syncthreads();
        sh[t] += x;
        __syncthreads();
    }
    lbase[t] = sh[t] - c;
    lcur[t] = 0;
    __syncthreads();
    for (int i = t; i < lim; i += 256) {
        int s = src[base + i], d = dst[base + i];
        int b = d >> BSH;
        int p = lbase[b] + atomicAdd(&lcur[b], 1);
        rec[p] = ((uint)(d & 511) << 17) | (uint)s;
        bkt[p] = (unsigned char)b;
    }
    __syncthreads();
    for (int j = t; j < lim; j += 256) {
        int b = bkt[j];
        ebuf[(size_t)gb[b] + (j - lbase[b])] = rec[j];
    }
}

// phase A: per-node histogram -> rp, dinv (parallel 512-wide scan).
// Bucket segment bounds recomputed in-block from bhist.
__global__ void k_bfinalA(const uint* __restrict__ ebuf, const int* __restrict__ bhist,
                          int* __restrict__ rp, float* __restrict__ dinv, int n, int e) {
    __shared__ int hcnt[512], hoff[512], sh[256], hB[256], sB[256];
    int b = blockIdx.x, t = threadIdx.x;
    int node0 = b << BSH;
    hB[t] = bhist[t];
    sB[t] = hB[t];
    __syncthreads();
    for (int off = 1; off < 256; off <<= 1) {
        int x = (t >= off) ? sB[t - off] : 0;
        __syncthreads();
        sB[t] += x;
        __syncthreads();
    }
    int e0 = sB[b] - hB[b];
    int m = hB[b];
    for (int j = t; j < 512; j += 256) hcnt[j] = 0;
    __syncthreads();
    for (int i = t; i < m; i += 256)
        atomicAdd(&hcnt[ebuf[e0 + i] >> 17], 1);
    __syncthreads();
    int a0 = hcnt[2 * t], a1 = hcnt[2 * t + 1];
    int ps = a0 + a1;
    sh[t] = ps;
    __syncthreads();
    for (int off = 1; off < 256; off <<= 1) {
        int x = (t >= off) ? sh[t - off] : 0;
        __syncthreads();
        sh[t] += x;
        __syncthreads();
    }
    int excl = sh[t] - ps;
    hoff[2 * t] = excl;
    hoff[2 * t + 1] = excl + a0;
    __syncthreads();
    for (int j = t; j < 512; j += 256) {
        int node = node0 + j;
        if (node < n) {
            rp[node] = e0 + hoff[j];
            dinv[node] = rsqrtf((float)(hcnt[j] + 1));
        }
    }
    if (b == 0 && t == 0) rp[n] = e;
}

// phase B: scatter edges into CSR order via LDS staging buffer, then linear
// coalesced write-out of erec. Direct-scatter fallback if bucket overflows.
#define BFB_CAP 12288
__global__ void k_bfinalB(const uint* __restrict__ ebuf, const int* __restrict__ bhist,
                          const int* __restrict__ rp, const float* __restrict__ dinv,
                          uint* __restrict__ erec, int n) {
    __shared__ int hcur[512], hB[256], sB[256];
    __shared__ uint recb[BFB_CAP];
    int b = blockIdx.x, t = threadIdx.x;
    int node0 = b << BSH;
    hB[t] = bhist[t];
    sB[t] = hB[t];
    __syncthreads();
    for (int off = 1; off < 256; off <<= 1) {
        int x = (t >= off) ? sB[t - off] : 0;
        __syncthreads();
        sB[t] += x;
        __syncthreads();
    }
    int e0 = sB[b] - hB[b];
    int m = hB[b];
    bool useLds = (m <= BFB_CAP);
    for (int j = t; j < 512; j += 256) {
        int node = node0 + j;
        hcur[j] = (node < n) ? rp[node] - e0 : 0;
    }
    __syncthreads();
    for (int i = t; i < m; i += 256) {
        uint u = ebuf[e0 + i];
        int s = (int)(u & 0x1FFFFu);
        int p = atomicAdd(&hcur[u >> 17], 1);
        uint db = __float_as_uint(dinv[s]);
        uint r = ((db + 0x10000u) & 0xFFFE0000u) | (uint)s;  // 15-bit dinv | 17-bit src
        if (useLds) recb[p] = r; else erec[e0 + p] = r;
    }
    __syncthreads();
    if (useLds)
        for (int i = t; i < m; i += 256) erec[e0 + i] = recb[i];
}

// ---------------- MFMA GEMM: C = BNReLU(A)[n,128] @ W, half-planar out ------
// MODE 0: A fp32 raw (layer 0). MODE 1: A bf16 + fused BN+ReLU (layers 1,2).
// A-tile loads non-temporal (read-once stream); Cout stores NORMAL on purpose
// (pre-warm L2 with the plane k_agg gathers from next).

template <int MODE>
__global__ __launch_bounds__(256) void k_gemm(
    const void* __restrict__ Ap, const ushort* __restrict__ WT,
    const float* __restrict__ stats, const float* __restrict__ g,
    const float* __restrict__ bt, float inv_n,
    ushort* __restrict__ Cout, int n) {
    __shared__ ushort As[64][136];
    __shared__ ushort Ws[128][136];
    __shared__ float bsc[128], bshf[128];
    int t = threadIdx.x;
    int wave = t >> 6, lane = t & 63;
    int rowBase = blockIdx.x * 64;

    if (MODE == 1) {
        if (t < 128) {
            float mu = stats[t] * inv_n;
            float var = stats[128 + t] * inv_n - mu * mu;
            float sc = g[t] * rsqrtf(var + EPSBN);
            bsc[t] = sc;
            bshf[t] = bt[t] - mu * sc;
        }
        __syncthreads();
    }

    if (MODE == 0) {
        const float* A = (const float*)Ap;
        for (int i = t; i < 64 * 32; i += 256) {
            int r = i >> 5, c4 = i & 31;
            int row = rowBase + r;
            f32x4 v = (f32x4){0.f, 0.f, 0.f, 0.f};
            if (row < n) v = __builtin_nontemporal_load((const f32x4*)(A + (size_t)row * H + c4 * 4));
            ushort4 o;
            o.x = f2b(v[0]); o.y = f2b(v[1]); o.z = f2b(v[2]); o.w = f2b(v[3]);
            *(ushort4*)(&As[r][c4 * 4]) = o;
        }
    } else {
        const ushort* A = (const ushort*)Ap;
        for (int i = t; i < 64 * 16; i += 256) {
            int r = i >> 4, c8 = i & 15;
            int row = rowBase + r;
            u32x4 v = (u32x4){0u, 0u, 0u, 0u};
            if (row < n) v = __builtin_nontemporal_load((const u32x4*)(A + (size_t)row * H + c8 * 8));
            const uint* pv = (const uint*)&v;
            ushort o[8];
#pragma unroll
            for (int j = 0; j < 4; ++j) {
                int f0 = c8 * 8 + 2 * j;
                float v0 = fmaxf(fmaf(blo(pv[j]), bsc[f0], bshf[f0]), 0.f);
                float v1 = fmaxf(fmaf(bhi(pv[j]), bsc[f0 + 1], bshf[f0 + 1]), 0.f);
                o[2 * j] = f2b(v0);
                o[2 * j + 1] = f2b(v1);
            }
            *(uint4*)(&As[r][c8 * 8]) = *(const uint4*)o;
        }
    }
    for (int i = t; i < 128 * 16; i += 256) {
        int j = i >> 4, c8 = i & 15;
        uint4 v = *(const uint4*)(WT + j * H + c8 * 8);
        *(uint4*)(&Ws[j][c8 * 8]) = v;
    }
    __syncthreads();

    int m = lane & 15, qd = lane >> 4;
    f32x4 acc[8];
#pragma unroll
    for (int c = 0; c < 8; ++c) acc[c] = (f32x4){0.f, 0.f, 0.f, 0.f};
#pragma unroll
    for (int kc = 0; kc < 4; ++kc) {
        int kof = kc * 32 + qd * 8;
        s16x8 afrag = *(const s16x8*)(&As[wave * 16 + m][kof]);
#pragma unroll
        for (int c = 0; c < 8; ++c) {
            s16x8 bfrag = *(const s16x8*)(&Ws[c * 16 + m][kof]);
            acc[c] = __builtin_amdgcn_mfma_f32_16x16x32_bf16(afrag, bfrag, acc[c], 0, 0, 0);
        }
    }
#pragma unroll
    for (int c = 0; c < 8; ++c) {
        int colI = c * 16 + m;
        int hh = colI >> 6, cq = colI & 63;
#pragma unroll
        for (int r = 0; r < 4; ++r) {
            int row = rowBase + wave * 16 + qd * 4 + r;
            if (row < n) Cout[((size_t)hh * NN + row) * 64 + cq] = f2b(acc[c][r]);
        }
    }
}

// ---------------- Aggregation + fused BN stats (half-split, per-sub nodes) --
// 8-lane subgroup <-> 128 B half-row (one full cache line); dynamic node
// ownership via LDS cursor; 256-node groups. half = blockIdx & 1 keeps each
// XCD's gather footprint to ONE 12.8 MB half-plane under round-robin dispatch.
// aggb stores non-temporal (write-once stream); erec loads NORMAL
// (sequential reuse — NT cost +18 MB FETCH in R6).

__global__ __launch_bounds__(256) void k_agg(
    const ushort* __restrict__ hwh, const int* __restrict__ rp,
    const uint* __restrict__ erec, const float* __restrict__ dinv,
    float* __restrict__ stats, ushort* __restrict__ aggb, int n) {
    __shared__ int cursor;
    __shared__ float lsum[64], lsq[64];
    int t = threadIdx.x;
    int lane = t & 63;
    int sl = lane & 7;       // lane within 8-lane sub
    int sub0 = lane & ~7;    // first lane of sub
    int half = blockIdx.x & 1;
    int nodeBase = (blockIdx.x >> 1) * 256;
    if (t == 0) cursor = 0;
    if (t < 64) { lsum[t] = 0.f; lsq[t] = 0.f; }
    __syncthreads();
    const uint4* hw4 = (const uint4*)hwh;  // half-planar: (half*NN + node)*8 + sl
    u32x4* agg4 = (u32x4*)aggb;            // interleaved: node*16 + half*8 + sl
    f32x2 ss[4], sq[4];
#pragma unroll
    for (int j = 0; j < 4; ++j) { ss[j] = (f32x2){0.f, 0.f}; sq[j] = (f32x2){0.f, 0.f}; }

    for (;;) {
        int ni = 0;
        if (sl == 0) ni = atomicAdd(&cursor, 1);
        ni = __shfl(ni, sub0);
        int node = nodeBase + ni;
        if (ni >= 256 || node >= n) break;
        float dn = dinv[node];
        f32x2 acc[4];
        {
            uint4 v = hw4[((size_t)half * NN + node) * 8 + sl];
            const uint* pv = (const uint*)&v;
#pragma unroll
            for (int j = 0; j < 4; ++j)
                acc[j] = (f32x2){dn * blo(pv[j]), dn * bhi(pv[j])};
        }
        int p = rp[node], pe = rp[node + 1];
        for (; p < pe; p += 4) {
            int i1 = p + 1 < pe ? p + 1 : pe - 1;
            int i2 = p + 2 < pe ? p + 2 : pe - 1;
            int i3 = p + 3 < pe ? p + 3 : pe - 1;
            uint r0 = erec[p], r1 = erec[i1], r2 = erec[i2], r3 = erec[i3];
            float w0 = __uint_as_float(r0 & 0xFFFE0000u);
            float w1 = (p + 1 < pe) ? __uint_as_float(r1 & 0xFFFE0000u) : 0.f;
            float w2 = (p + 2 < pe) ? __uint_as_float(r2 & 0xFFFE0000u) : 0.f;
            float w3 = (p + 3 < pe) ? __uint_as_float(r3 & 0xFFFE0000u) : 0.f;
            uint4 v0 = hw4[((size_t)half * NN + (r0 & 0x1FFFFu)) * 8 + sl];
            uint4 v1 = hw4[((size_t)half * NN + (r1 & 0x1FFFFu)) * 8 + sl];
            uint4 v2 = hw4[((size_t)half * NN + (r2 & 0x1FFFFu)) * 8 + sl];
            uint4 v3 = hw4[((size_t)half * NN + (r3 & 0x1FFFFu)) * 8 + sl];
            const uint* p0 = (const uint*)&v0;
            const uint* p1 = (const uint*)&v1;
            const uint* p2 = (const uint*)&v2;
            const uint* p3 = (const uint*)&v3;
            f32x2 wv0 = (f32x2){w0, w0}, wv1 = (f32x2){w1, w1};
            f32x2 wv2 = (f32x2){w2, w2}, wv3 = (f32x2){w3, w3};
#pragma unroll
            for (int j = 0; j < 4; ++j) {
                acc[j] = __builtin_elementwise_fma(wv0, (f32x2){blo(p0[j]), bhi(p0[j])}, acc[j]);
                acc[j] = __builtin_elementwise_fma(wv1, (f32x2){blo(p1[j]), bhi(p1[j])}, acc[j]);
                acc[j] = __builtin_elementwise_fma(wv2, (f32x2){blo(p2[j]), bhi(p2[j])}, acc[j]);
                acc[j] = __builtin_elementwise_fma(wv3, (f32x2){blo(p3[j]), bhi(p3[j])}, acc[j]);
            }
        }
        u32x4 o;
        uint* po = (uint*)&o;
        f32x2 dn2 = (f32x2){dn, dn};
#pragma unroll
        for (int j = 0; j < 4; ++j) {
            f32x2 ov = dn2 * acc[j];
            ss[j] += ov;
            sq[j] = __builtin_elementwise_fma(ov, ov, sq[j]);
            po[j] = (uint)f2b(ov.x) | ((uint)f2b(ov.y) << 16);
        }
        __builtin_nontemporal_store(o, agg4 + (size_t)node * 16 + half * 8 + sl);
    }
#pragma unroll
    for (int j = 0; j < 4; ++j) {
        atomicAdd(&lsum[sl * 8 + 2 * j], ss[j].x);
        atomicAdd(&lsum[sl * 8 + 2 * j + 1], ss[j].y);
        atomicAdd(&lsq[sl * 8 + 2 * j], sq[j].x);
        atomicAdd(&lsq[sl * 8 + 2 * j + 1], sq[j].y);
    }
    __syncthreads();
    if (t < 64) {
        atomicAdd(&stats[half * 64 + t], lsum[t]);
        atomicAdd(&stats[128 + half * 64 + t], lsq[t]);
    }
}

// ---------------- Pooling (BN+ReLU inline, NT loads, inlined graph bounds) --

__global__ __launch_bounds__(256) void k_pool(
    const ushort* __restrict__ aggall, const float* __restrict__ statsall,
    const float* __restrict__ g1, const float* __restrict__ bt1,
    const float* __restrict__ gc, const float* __restrict__ btc,
    const int* __restrict__ batch, int n, float* __restrict__ pooled,
    float inv_n) {
    __shared__ float bsc[64], bshf[64];
    __shared__ float red[32][64];
    int g = blockIdx.x;
    int s = blockIdx.y;              // feature slice: 64 feats
    int sec = s >> 1;                // section (layer) 0..2
    int c = threadIdx.x & 7;         // uint4 chunk within slice
    int rg = threadIdx.x >> 3;       // row lane 0..31
    int t = threadIdx.x;

    if (t < 64) {
        int feat = (s & 1) * 64 + t;  // feature within section (0..127)
        const float* st = statsall + sec * 256;
        float mu = st[feat] * inv_n;
        float var = st[128 + feat] * inv_n - mu * mu;
        float gm = (sec == 0) ? g1[feat] : gc[(sec - 1) * H + feat];
        float bm = (sec == 0) ? bt1[feat] : btc[(sec - 1) * H + feat];
        float sc = gm * rsqrtf(var + EPSBN);
        bsc[t] = sc;
        bshf[t] = bm - mu * sc;
    }

    // graph bounds: two inlined binary searches on sorted batch (former k_gbound)
    int lo = 0, hi = n;
    while (lo < hi) { int mid = (lo + hi) >> 1; if (batch[mid] < g) lo = mid + 1; else hi = mid; }
    int r0 = lo;
    hi = n;
    while (lo < hi) { int mid = (lo + hi) >> 1; if (batch[mid] < g + 1) lo = mid + 1; else hi = mid; }
    int r1 = lo;
    __syncthreads();

    const u32x4* a4 = (const u32x4*)aggall;
    size_t secBase = (size_t)sec * NN * 16;
    int cOff = (s & 1) * 8 + c;
    float acc[8];
#pragma unroll
    for (int j = 0; j < 8; ++j) acc[j] = 0.f;
    for (int r = r0 + rg; r < r1; r += 32) {
        u32x4 v = __builtin_nontemporal_load(a4 + secBase + (size_t)r * 16 + cOff);
        const uint* pv = (const uint*)&v;
#pragma unroll
        for (int j = 0; j < 4; ++j) {
            int f0 = c * 8 + 2 * j;
            acc[2 * j]     += fmaxf(fmaf(blo(pv[j]), bsc[f0], bshf[f0]), 0.f);
            acc[2 * j + 1] += fmaxf(fmaf(bhi(pv[j]), bsc[f0 + 1], bshf[f0 + 1]), 0.f);
        }
    }
#pragma unroll
    for (int j = 0; j < 8; ++j) red[rg][c * 8 + j] = acc[j];
    __syncthreads();
    if (t < 64) {
        float sum = 0.f;
#pragma unroll
        for (int rr = 0; rr < 32; ++rr) sum += red[rr][t];
        float cnt = (float)(r1 - r0);
        pooled[g * LH + s * 64 + t] = sum / fmaxf(cnt, 1.f);
    }
}

// ---------------- MLP head ----------------

// k_mlp1 also accumulates z batch-stats via global atomics (former k_zstats)
__global__ void k_mlp1(const float* __restrict__ pooled, const float* __restrict__ Wl1,
                       const float* __restrict__ bl1, float* __restrict__ z,
                       float* __restrict__ zst) {
    __shared__ float row[LH];
    int g = blockIdx.x;
    int j = threadIdx.x;  // 128 threads
    for (int k = j; k < LH; k += H) row[k] = pooled[g * LH + k];
    __syncthreads();
    float acc = bl1[j];
    for (int k = 0; k < LH; ++k) acc += row[k] * Wl1[k * H + j];
    z[g * H + j] = acc;
    atomicAdd(&zst[j], acc);
    atomicAdd(&zst[128 + j], acc * acc);
}

__global__ void k_mlp2(const float* __restrict__ z, const float* __restrict__ st,
                       const float* __restrict__ gl, const float* __restrict__ btl,
                       const float* __restrict__ Wl2, const float* __restrict__ bl2,
                       float* __restrict__ out) {
    __shared__ float zn[H];
    __shared__ float logit[CC];
    int g = blockIdx.x;
    int t = threadIdx.x;  // 128 threads
    float mu = st[t] * (1.f / GG);
    float var = st[128 + t] * (1.f / GG) - mu * mu;
    float v = (z[g * H + t] - mu) * rsqrtf(var + EPSBN) * gl[t] + btl[t];
    zn[t] = fmaxf(v, 0.f);
    __syncthreads();
    if (t < CC) {
        float acc = bl2[t];
        for (int k = 0; k < H; ++k) acc += zn[k] * Wl2[k * CC + t];
        logit[t] = acc;
    }
    __syncthreads();
    if (t == 0) {
        float m = -1e30f;
        for (int c = 0; c < CC; ++c) m = fmaxf(m, logit[c]);
        float se = 0.f;
        for (int c = 0; c < CC; ++c) se += expf(logit[c] - m);
        float lse = m + logf(se);
        for (int c = 0; c < CC; ++c) out[g * CC + c] = logit[c] - lse;
    }
}

// ---------------- launch ----------------

extern "C" void kernel_launch(void* const* d_in, const int* in_sizes, int n_in,
                              void* d_out, int out_size, void* d_ws, size_t ws_size,
                              hipStream_t stream) {
    const float* x   = (const float*)d_in[0];
    const int*   ei  = (const int*)d_in[1];
    const int*   bat = (const int*)d_in[2];
    const float* W1  = (const float*)d_in[3];
    const float* g1  = (const float*)d_in[5];
    const float* bt1 = (const float*)d_in[6];
    const float* Wc  = (const float*)d_in[7];
    const float* gc  = (const float*)d_in[9];
    const float* btc = (const float*)d_in[10];
    const float* Wl1 = (const float*)d_in[11];
    const float* bl1 = (const float*)d_in[12];
    const float* gl  = (const float*)d_in[13];
    const float* btl = (const float*)d_in[14];
    const float* Wl2 = (const float*)d_in[15];
    const float* bl2 = (const float*)d_in[16];
    float* out = (float*)d_out;

    const int n = in_sizes[2];
    const int e = in_sizes[1] / 2;
    const int* src = ei;
    const int* dst = ei + e;
    const int nbuck = (n + 511) / 512;  // <= 256
    const float inv_n = 1.0f / (float)n;

    size_t off = 0;
    char* base = (char*)d_ws;
    auto take = [&](size_t nbytes) -> void* {
        void* p = base + off;
        off += (nbytes + 255) & ~(size_t)255;
        return p;
    };
    int*    rp      = (int*)take((size_t)(NN + 1) * 4);
    float*  dinv    = (float*)take((size_t)NN * 4);
    // contiguous zero-init region: bhist, bcursor, stats, zst (one memset)
    int*    bhist   = (int*)take(1024);
    int*    bcursor = (int*)take(1024);
    float*  stats   = (float*)take(3 * 1024);
    float*  zst     = (float*)take(1024);
    uint*   ebuf    = (uint*)take((size_t)NE * 4);
    uint*   erec    = (uint*)take((size_t)NE * 4);
    ushort* WTb     = (ushort*)take((size_t)3 * H * H * 2);
    ushort* hwb     = (ushort*)take((size_t)NN * H * 2);
    ushort* aggb    = (ushort*)take((size_t)3 * NN * H * 2);
    float*  pooled  = (float*)take((size_t)GG * LH * 4);
    float*  z       = (float*)take((size_t)GG * H * 4);

    // ---- single zero-init (bhist + bcursor + stats + zst, contiguous) ----
    hipMemsetAsync(bhist, 0, 1024 + 1024 + 3 * 1024 + 1024, stream);

    // ---- fused weight transpose + bucket histogram ----
    k_wt_bhist<<<448, 256, 0, stream>>>(W1, Wc, WTb, dst, bhist, e, nbuck);

    // ---- bucketed CSR build (bucket bases recomputed in-block) ----
    k_bin<<<(e + 4095) / 4096, 256, 0, stream>>>(src, dst, bhist, bcursor, ebuf, e);
    k_bfinalA<<<nbuck, 256, 0, stream>>>(ebuf, bhist, rp, dinv, n, e);
    k_bfinalB<<<nbuck, 256, 0, stream>>>(ebuf, bhist, rp, dinv, erec, n);

    // ---- 3 GCN layers (BN+ReLU of layer l-1 fused into layer l's GEMM) ----
    for (int l = 0; l < 3; ++l) {
        const ushort* WT = WTb + (size_t)l * H * H;

        if (l == 0) {
            k_gemm<0><<<(n + 63) / 64, 256, 0, stream>>>(
                x, WT, nullptr, nullptr, nullptr, inv_n, hwb, n);
        } else {
            const float* gm  = (l == 1) ? g1 : gc;
            const float* btm = (l == 1) ? bt1 : btc;
            k_gemm<1><<<(n + 63) / 64, 256, 0, stream>>>(
                aggb + (size_t)(l - 1) * NN * H, WT, stats + (size_t)(l - 1) * 256,
                gm, btm, inv_n, hwb, n);
        }
        k_agg<<<((n + 255) / 256) * 2, 256, 0, stream>>>(
            hwb, rp, erec, dinv, stats + (size_t)l * 256, aggb + (size_t)l * NN * H, n);
    }

    // ---- pooling (graph bounds inlined) ----
    {
        dim3 pg(GG, 6);
        k_pool<<<pg, 256, 0, stream>>>(aggb, stats, g1, bt1, gc, btc, bat, n,
                                       pooled, inv_n);
    }

    // ---- MLP head (z-stats fused into mlp1) ----
    k_mlp1<<<GG, H, 0, stream>>>(pooled, Wl1, bl1, z, zst);
    k_mlp2<<<GG, H, 0, stream>>>(z, zst, gl, btl, Wl2, bl2, out);
}

// Round 11
// 499.239 us; speedup vs baseline: 1.0399x; 1.0399x over previous
//
#include <hip/hip_runtime.h>
#include <math.h>

#define NN 100000
#define NE 1600000
#define H 128
#define LH 384
#define GG 512
#define CC 10
#define EPSBN 1e-5f
#define BSH 9  // bucket shift: 512 nodes per bucket

typedef __attribute__((ext_vector_type(4))) float f32x4;
typedef __attribute__((ext_vector_type(2))) float f32x2;
typedef __attribute__((ext_vector_type(8))) short s16x8;
typedef __attribute__((ext_vector_type(4))) uint u32x4;
typedef unsigned long long u64;

__device__ inline ushort f2b(float f) {
    uint u = __float_as_uint(f);
    uint r = (u + 0x7FFFu + ((u >> 16) & 1u)) >> 16;
    return (ushort)r;
}
__device__ inline float b2f(ushort b) { return __uint_as_float(((uint)b) << 16); }
__device__ inline float blo(uint v) { return __uint_as_float(v << 16); }
__device__ inline float bhi(uint v) { return __uint_as_float(v & 0xFFFF0000u); }

// ---------------- fused: W transpose/convert + edge bucket histogram -------
// blocks [0,192): WT[mat][j][k] = bf16(W[mat][k][j])  (2 (mat,k) pairs/block)
// blocks [192,448): 256-block grid-stride histogram of dst buckets

__global__ void k_wt_bhist(const float* __restrict__ W1, const float* __restrict__ Wc,
                           ushort* __restrict__ WT,
                           const int* __restrict__ dst, int* __restrict__ bhist,
                           int e, int nbuck) {
    int t = threadIdx.x;
    if (blockIdx.x < 192) {
        int idx = blockIdx.x * 2 + (t >> 7);  // 0..383 = mat*128 + k
        int mat = idx >> 7;
        int k = idx & 127;
        int j = t & 127;
        const float* W = (mat == 0) ? W1 : Wc + (size_t)(mat - 1) * H * H;
        WT[(size_t)mat * H * H + j * H + k] = f2b(W[(size_t)k * H + j]);
        return;
    }
    __shared__ int lh[256];
    lh[t] = 0;
    __syncthreads();
    int hb = blockIdx.x - 192;
    for (int i = hb * 256 + t; i < e; i += 256 * 256)
        atomicAdd(&lh[dst[i] >> BSH], 1);
    __syncthreads();
    int v = lh[t];
    if (t < nbuck && v) atomicAdd(&bhist[t], v);
}

// block-aggregated scatter, LDS-staged: records binned into LDS by bucket,
// then streamed out in bucket order -> coalesced runs. Bucket bases are
// recomputed in-block from bhist (256-entry LDS scan); bcursor is zero-based.
// packed u32 record: (dst & 511) << 17 | src
__global__ void k_bin(const int* __restrict__ src, const int* __restrict__ dst,
                      const int* __restrict__ bhist, int* __restrict__ bcursor,
                      uint* __restrict__ ebuf, int e) {
    __shared__ int lh[256], gb[256], lbase[256], lcur[256], sh[256];
    __shared__ uint rec[4096];
    __shared__ unsigned char bkt[4096];
    int t = threadIdx.x;
    // bucket base = exclusive scan of bhist
    int hv = bhist[t];
    sh[t] = hv;
    __syncthreads();
    for (int off = 1; off < 256; off <<= 1) {
        int x = (t >= off) ? sh[t - off] : 0;
        __syncthreads();
        sh[t] += x;
        __syncthreads();
    }
    int rbb = sh[t] - hv;  // bbase[t]
    __syncthreads();
    int base = blockIdx.x * 4096;
    int lim = e - base; if (lim > 4096) lim = 4096;
    lh[t] = 0;
    __syncthreads();
    for (int i = t; i < lim; i += 256)
        atomicAdd(&lh[dst[base + i] >> BSH], 1);
    __syncthreads();
    int c = lh[t];
    if (c) gb[t] = rbb + atomicAdd(&bcursor[t], c);
    sh[t] = c;
    __syncthreads();
    for (int off = 1; off < 256; off <<= 1) {
        int x = (t >= off) ? sh[t - off] : 0;
        __syncthreads();
        sh[t] += x;
        __syncthreads();
    }
    lbase[t] = sh[t] - c;
    lcur[t] = 0;
    __syncthreads();
    for (int i = t; i < lim; i += 256) {
        int s = src[base + i], d = dst[base + i];
        int b = d >> BSH;
        int p = lbase[b] + atomicAdd(&lcur[b], 1);
        rec[p] = ((uint)(d & 511) << 17) | (uint)s;
        bkt[p] = (unsigned char)b;
    }
    __syncthreads();
    for (int j = t; j < lim; j += 256) {
        int b = bkt[j];
        ebuf[(size_t)gb[b] + (j - lbase[b])] = rec[j];
    }
}

// phase A: per-node histogram -> rp, dinv (parallel 512-wide scan).
// Bucket segment bounds recomputed in-block from bhist.
__global__ void k_bfinalA(const uint* __restrict__ ebuf, const int* __restrict__ bhist,
                          int* __restrict__ rp, float* __restrict__ dinv, int n, int e) {
    __shared__ int hcnt[512], hoff[512], sh[256], hB[256], sB[256];
    int b = blockIdx.x, t = threadIdx.x;
    int node0 = b << BSH;
    hB[t] = bhist[t];
    sB[t] = hB[t];
    __syncthreads();
    for (int off = 1; off < 256; off <<= 1) {
        int x = (t >= off) ? sB[t - off] : 0;
        __syncthreads();
        sB[t] += x;
        __syncthreads();
    }
    int e0 = sB[b] - hB[b];
    int m = hB[b];
    for (int j = t; j < 512; j += 256) hcnt[j] = 0;
    __syncthreads();
    for (int i = t; i < m; i += 256)
        atomicAdd(&hcnt[ebuf[e0 + i] >> 17], 1);
    __syncthreads();
    int a0 = hcnt[2 * t], a1 = hcnt[2 * t + 1];
    int ps = a0 + a1;
    sh[t] = ps;
    __syncthreads();
    for (int off = 1; off < 256; off <<= 1) {
        int x = (t >= off) ? sh[t - off] : 0;
        __syncthreads();
        sh[t] += x;
        __syncthreads();
    }
    int excl = sh[t] - ps;
    hoff[2 * t] = excl;
    hoff[2 * t + 1] = excl + a0;
    __syncthreads();
    for (int j = t; j < 512; j += 256) {
        int node = node0 + j;
        if (node < n) {
            rp[node] = e0 + hoff[j];
            dinv[node] = rsqrtf((float)(hcnt[j] + 1));
        }
    }
    if (b == 0 && t == 0) rp[n] = e;
}

// phase B: scatter edges into CSR order via LDS staging buffer, then linear
// coalesced write-out of erec. Direct-scatter fallback if bucket overflows.
#define BFB_CAP 12288
__global__ void k_bfinalB(const uint* __restrict__ ebuf, const int* __restrict__ bhist,
                          const int* __restrict__ rp, const float* __restrict__ dinv,
                          uint* __restrict__ erec, int n) {
    __shared__ int hcur[512], hB[256], sB[256];
    __shared__ uint recb[BFB_CAP];
    int b = blockIdx.x, t = threadIdx.x;
    int node0 = b << BSH;
    hB[t] = bhist[t];
    sB[t] = hB[t];
    __syncthreads();
    for (int off = 1; off < 256; off <<= 1) {
        int x = (t >= off) ? sB[t - off] : 0;
        __syncthreads();
        sB[t] += x;
        __syncthreads();
    }
    int e0 = sB[b] - hB[b];
    int m = hB[b];
    bool useLds = (m <= BFB_CAP);
    for (int j = t; j < 512; j += 256) {
        int node = node0 + j;
        hcur[j] = (node < n) ? rp[node] - e0 : 0;
    }
    __syncthreads();
    for (int i = t; i < m; i += 256) {
        uint u = ebuf[e0 + i];
        int s = (int)(u & 0x1FFFFu);
        int p = atomicAdd(&hcur[u >> 17], 1);
        uint db = __float_as_uint(dinv[s]);
        uint r = ((db + 0x10000u) & 0xFFFE0000u) | (uint)s;  // 15-bit dinv | 17-bit src
        if (useLds) recb[p] = r; else erec[e0 + p] = r;
    }
    __syncthreads();
    if (useLds)
        for (int i = t; i < m; i += 256) erec[e0 + i] = recb[i];
}

// ---------------- MFMA GEMM: C = BNReLU(A)[n,128] @ W, half-planar out ------
// MODE 0: A fp32 raw (layer 0). MODE 1: A bf16 + fused BN+ReLU (layers 1,2).
// A-tile loads non-temporal (read-once stream); Cout stores NORMAL on purpose
// (pre-warm L2 with the plane k_agg gathers from next).

template <int MODE>
__global__ __launch_bounds__(256) void k_gemm(
    const void* __restrict__ Ap, const ushort* __restrict__ WT,
    const float* __restrict__ stats, const float* __restrict__ g,
    const float* __restrict__ bt, float inv_n,
    ushort* __restrict__ Cout, int n) {
    __shared__ ushort As[64][136];
    __shared__ ushort Ws[128][136];
    __shared__ float bsc[128], bshf[128];
    int t = threadIdx.x;
    int wave = t >> 6, lane = t & 63;
    int rowBase = blockIdx.x * 64;

    if (MODE == 1) {
        if (t < 128) {
            float mu = stats[t] * inv_n;
            float var = stats[128 + t] * inv_n - mu * mu;
            float sc = g[t] * rsqrtf(var + EPSBN);
            bsc[t] = sc;
            bshf[t] = bt[t] - mu * sc;
        }
        __syncthreads();
    }

    if (MODE == 0) {
        const float* A = (const float*)Ap;
        for (int i = t; i < 64 * 32; i += 256) {
            int r = i >> 5, c4 = i & 31;
            int row = rowBase + r;
            f32x4 v = (f32x4){0.f, 0.f, 0.f, 0.f};
            if (row < n) v = __builtin_nontemporal_load((const f32x4*)(A + (size_t)row * H + c4 * 4));
            ushort4 o;
            o.x = f2b(v[0]); o.y = f2b(v[1]); o.z = f2b(v[2]); o.w = f2b(v[3]);
            *(ushort4*)(&As[r][c4 * 4]) = o;
        }
    } else {
        const ushort* A = (const ushort*)Ap;
        for (int i = t; i < 64 * 16; i += 256) {
            int r = i >> 4, c8 = i & 15;
            int row = rowBase + r;
            u32x4 v = (u32x4){0u, 0u, 0u, 0u};
            if (row < n) v = __builtin_nontemporal_load((const u32x4*)(A + (size_t)row * H + c8 * 8));
            const uint* pv = (const uint*)&v;
            ushort o[8];
#pragma unroll
            for (int j = 0; j < 4; ++j) {
                int f0 = c8 * 8 + 2 * j;
                float v0 = fmaxf(fmaf(blo(pv[j]), bsc[f0], bshf[f0]), 0.f);
                float v1 = fmaxf(fmaf(bhi(pv[j]), bsc[f0 + 1], bshf[f0 + 1]), 0.f);
                o[2 * j] = f2b(v0);
                o[2 * j + 1] = f2b(v1);
            }
            *(uint4*)(&As[r][c8 * 8]) = *(const uint4*)o;
        }
    }
    for (int i = t; i < 128 * 16; i += 256) {
        int j = i >> 4, c8 = i & 15;
        uint4 v = *(const uint4*)(WT + j * H + c8 * 8);
        *(uint4*)(&Ws[j][c8 * 8]) = v;
    }
    __syncthreads();

    int m = lane & 15, qd = lane >> 4;
    f32x4 acc[8];
#pragma unroll
    for (int c = 0; c < 8; ++c) acc[c] = (f32x4){0.f, 0.f, 0.f, 0.f};
#pragma unroll
    for (int kc = 0; kc < 4; ++kc) {
        int kof = kc * 32 + qd * 8;
        s16x8 afrag = *(const s16x8*)(&As[wave * 16 + m][kof]);
#pragma unroll
        for (int c = 0; c < 8; ++c) {
            s16x8 bfrag = *(const s16x8*)(&Ws[c * 16 + m][kof]);
            acc[c] = __builtin_amdgcn_mfma_f32_16x16x32_bf16(afrag, bfrag, acc[c], 0, 0, 0);
        }
    }
#pragma unroll
    for (int c = 0; c < 8; ++c) {
        int colI = c * 16 + m;
        int hh = colI >> 6, cq = colI & 63;
#pragma unroll
        for (int r = 0; r < 4; ++r) {
            int row = rowBase + wave * 16 + qd * 4 + r;
            if (row < n) Cout[((size_t)hh * NN + row) * 64 + cq] = f2b(acc[c][r]);
        }
    }
}

// ---------------- Aggregation + fused BN stats (half-split, per-sub nodes) --
// 8-lane subgroup <-> 128 B half-row (one full cache line); dynamic node
// ownership via LDS cursor; 256-node groups. half = blockIdx & 1 keeps each
// XCD's gather footprint to ONE 12.8 MB half-plane under round-robin dispatch.
// aggb stores non-temporal (write-once stream); erec loads NORMAL
// (sequential reuse — NT cost +18 MB FETCH in R6).

__global__ __launch_bounds__(256) void k_agg(
    const ushort* __restrict__ hwh, const int* __restrict__ rp,
    const uint* __restrict__ erec, const float* __restrict__ dinv,
    float* __restrict__ stats, ushort* __restrict__ aggb, int n) {
    __shared__ int cursor;
    __shared__ float lsum[64], lsq[64];
    int t = threadIdx.x;
    int lane = t & 63;
    int sl = lane & 7;       // lane within 8-lane sub
    int sub0 = lane & ~7;    // first lane of sub
    int half = blockIdx.x & 1;
    int nodeBase = (blockIdx.x >> 1) * 256;
    if (t == 0) cursor = 0;
    if (t < 64) { lsum[t] = 0.f; lsq[t] = 0.f; }
    __syncthreads();
    const uint4* hw4 = (const uint4*)hwh;  // half-planar: (half*NN + node)*8 + sl
    u32x4* agg4 = (u32x4*)aggb;            // interleaved: node*16 + half*8 + sl
    f32x2 ss[4], sq[4];
#pragma unroll
    for (int j = 0; j < 4; ++j) { ss[j] = (f32x2){0.f, 0.f}; sq[j] = (f32x2){0.f, 0.f}; }

    for (;;) {
        int ni = 0;
        if (sl == 0) ni = atomicAdd(&cursor, 1);
        ni = __shfl(ni, sub0);
        int node = nodeBase + ni;
        if (ni >= 256 || node >= n) break;
        float dn = dinv[node];
        f32x2 acc[4];
        {
            uint4 v = hw4[((size_t)half * NN + node) * 8 + sl];
            const uint* pv = (const uint*)&v;
#pragma unroll
            for (int j = 0; j < 4; ++j)
                acc[j] = (f32x2){dn * blo(pv[j]), dn * bhi(pv[j])};
        }
        int p = rp[node], pe = rp[node + 1];
        for (; p < pe; p += 4) {
            int i1 = p + 1 < pe ? p + 1 : pe - 1;
            int i2 = p + 2 < pe ? p + 2 : pe - 1;
            int i3 = p + 3 < pe ? p + 3 : pe - 1;
            uint r0 = erec[p], r1 = erec[i1], r2 = erec[i2], r3 = erec[i3];
            float w0 = __uint_as_float(r0 & 0xFFFE0000u);
            float w1 = (p + 1 < pe) ? __uint_as_float(r1 & 0xFFFE0000u) : 0.f;
            float w2 = (p + 2 < pe) ? __uint_as_float(r2 & 0xFFFE0000u) : 0.f;
            float w3 = (p + 3 < pe) ? __uint_as_float(r3 & 0xFFFE0000u) : 0.f;
            uint4 v0 = hw4[((size_t)half * NN + (r0 & 0x1FFFFu)) * 8 + sl];
            uint4 v1 = hw4[((size_t)half * NN + (r1 & 0x1FFFFu)) * 8 + sl];
            uint4 v2 = hw4[((size_t)half * NN + (r2 & 0x1FFFFu)) * 8 + sl];
            uint4 v3 = hw4[((size_t)half * NN + (r3 & 0x1FFFFu)) * 8 + sl];
            const uint* p0 = (const uint*)&v0;
            const uint* p1 = (const uint*)&v1;
            const uint* p2 = (const uint*)&v2;
            const uint* p3 = (const uint*)&v3;
            f32x2 wv0 = (f32x2){w0, w0}, wv1 = (f32x2){w1, w1};
            f32x2 wv2 = (f32x2){w2, w2}, wv3 = (f32x2){w3, w3};
#pragma unroll
            for (int j = 0; j < 4; ++j) {
                acc[j] = __builtin_elementwise_fma(wv0, (f32x2){blo(p0[j]), bhi(p0[j])}, acc[j]);
                acc[j] = __builtin_elementwise_fma(wv1, (f32x2){blo(p1[j]), bhi(p1[j])}, acc[j]);
                acc[j] = __builtin_elementwise_fma(wv2, (f32x2){blo(p2[j]), bhi(p2[j])}, acc[j]);
                acc[j] = __builtin_elementwise_fma(wv3, (f32x2){blo(p3[j]), bhi(p3[j])}, acc[j]);
            }
        }
        u32x4 o;
        uint* po = (uint*)&o;
        f32x2 dn2 = (f32x2){dn, dn};
#pragma unroll
        for (int j = 0; j < 4; ++j) {
            f32x2 ov = dn2 * acc[j];
            ss[j] += ov;
            sq[j] = __builtin_elementwise_fma(ov, ov, sq[j]);
            po[j] = (uint)f2b(ov.x) | ((uint)f2b(ov.y) << 16);
        }
        __builtin_nontemporal_store(o, agg4 + (size_t)node * 16 + half * 8 + sl);
    }
#pragma unroll
    for (int j = 0; j < 4; ++j) {
        atomicAdd(&lsum[sl * 8 + 2 * j], ss[j].x);
        atomicAdd(&lsum[sl * 8 + 2 * j + 1], ss[j].y);
        atomicAdd(&lsq[sl * 8 + 2 * j], sq[j].x);
        atomicAdd(&lsq[sl * 8 + 2 * j + 1], sq[j].y);
    }
    __syncthreads();
    if (t < 64) {
        atomicAdd(&stats[half * 64 + t], lsum[t]);
        atomicAdd(&stats[128 + half * 64 + t], lsq[t]);
    }
}

// ---------------- Pooling (BN+ReLU inline, vectorized, NT loads) -----------

__global__ void k_gbound(const int* __restrict__ batch, int* __restrict__ gptr, int n) {
    int g = blockIdx.x * 256 + threadIdx.x;
    if (g > GG) return;
    int lo = 0, hi = n;
    while (lo < hi) {
        int mid = (lo + hi) >> 1;
        if (batch[mid] < g) lo = mid + 1; else hi = mid;
    }
    gptr[g] = lo;
}

__global__ __launch_bounds__(256) void k_pool(
    const ushort* __restrict__ aggall, const float* __restrict__ statsall,
    const float* __restrict__ g1, const float* __restrict__ bt1,
    const float* __restrict__ gc, const float* __restrict__ btc,
    const int* __restrict__ gptr, float* __restrict__ pooled, float inv_n) {
    __shared__ float bsc[64], bshf[64];
    __shared__ float red[32][64];
    int g = blockIdx.x;
    int s = blockIdx.y;              // feature slice: 64 feats
    int sec = s >> 1;                // section (layer) 0..2
    int c = threadIdx.x & 7;         // uint4 chunk within slice
    int rg = threadIdx.x >> 3;       // row lane 0..31
    int t = threadIdx.x;

    if (t < 64) {
        int feat = (s & 1) * 64 + t;  // feature within section (0..127)
        const float* st = statsall + sec * 256;
        float mu = st[feat] * inv_n;
        float var = st[128 + feat] * inv_n - mu * mu;
        float gm = (sec == 0) ? g1[feat] : gc[(sec - 1) * H + feat];
        float bm = (sec == 0) ? bt1[feat] : btc[(sec - 1) * H + feat];
        float sc = gm * rsqrtf(var + EPSBN);
        bsc[t] = sc;
        bshf[t] = bm - mu * sc;
    }
    __syncthreads();

    int r0 = gptr[g], r1 = gptr[g + 1];
    const u32x4* a4 = (const u32x4*)aggall;
    size_t secBase = (size_t)sec * NN * 16;
    int cOff = (s & 1) * 8 + c;
    float acc[8];
#pragma unroll
    for (int j = 0; j < 8; ++j) acc[j] = 0.f;
    for (int r = r0 + rg; r < r1; r += 32) {
        u32x4 v = __builtin_nontemporal_load(a4 + secBase + (size_t)r * 16 + cOff);
        const uint* pv = (const uint*)&v;
#pragma unroll
        for (int j = 0; j < 4; ++j) {
            int f0 = c * 8 + 2 * j;
            acc[2 * j]     += fmaxf(fmaf(blo(pv[j]), bsc[f0], bshf[f0]), 0.f);
            acc[2 * j + 1] += fmaxf(fmaf(bhi(pv[j]), bsc[f0 + 1], bshf[f0 + 1]), 0.f);
        }
    }
#pragma unroll
    for (int j = 0; j < 8; ++j) red[rg][c * 8 + j] = acc[j];
    __syncthreads();
    if (t < 64) {
        float sum = 0.f;
#pragma unroll
        for (int rr = 0; rr < 32; ++rr) sum += red[rr][t];
        float cnt = (float)(r1 - r0);
        pooled[g * LH + s * 64 + t] = sum / fmaxf(cnt, 1.f);
    }
}

// ---------------- MLP head ----------------

__global__ void k_mlp1(const float* __restrict__ pooled, const float* __restrict__ Wl1,
                       const float* __restrict__ bl1, float* __restrict__ z) {
    __shared__ float row[LH];
    int g = blockIdx.x;
    int j = threadIdx.x;  // 128 threads
    for (int k = j; k < LH; k += H) row[k] = pooled[g * LH + k];
    __syncthreads();
    float acc = bl1[j];
    for (int k = 0; k < LH; ++k) acc += row[k] * Wl1[k * H + j];
    z[g * H + j] = acc;
}

// parallel z stats: 16 blocks x 32 graphs each, atomic merge into st
__global__ void k_zstats(const float* __restrict__ z, float* __restrict__ st) {
    int j = threadIdx.x;  // 128 threads
    int g0 = blockIdx.x * 32;
    float s = 0.f, q = 0.f;
    for (int g = g0; g < g0 + 32; ++g) {
        float v = z[g * H + j];
        s += v;
        q += v * v;
    }
    atomicAdd(&st[j], s);
    atomicAdd(&st[128 + j], q);
}

__global__ void k_mlp2(const float* __restrict__ z, const float* __restrict__ st,
                       const float* __restrict__ gl, const float* __restrict__ btl,
                       const float* __restrict__ Wl2, const float* __restrict__ bl2,
                       float* __restrict__ out) {
    __shared__ float zn[H];
    __shared__ float logit[CC];
    int g = blockIdx.x;
    int t = threadIdx.x;  // 128 threads
    float mu = st[t] * (1.f / GG);
    float var = st[128 + t] * (1.f / GG) - mu * mu;
    float v = (z[g * H + t] - mu) * rsqrtf(var + EPSBN) * gl[t] + btl[t];
    zn[t] = fmaxf(v, 0.f);
    __syncthreads();
    if (t < CC) {
        float acc = bl2[t];
        for (int k = 0; k < H; ++k) acc += zn[k] * Wl2[k * CC + t];
        logit[t] = acc;
    }
    __syncthreads();
    if (t == 0) {
        float m = -1e30f;
        for (int c = 0; c < CC; ++c) m = fmaxf(m, logit[c]);
        float se = 0.f;
        for (int c = 0; c < CC; ++c) se += expf(logit[c] - m);
        float lse = m + logf(se);
        for (int c = 0; c < CC; ++c) out[g * CC + c] = logit[c] - lse;
    }
}

// ---------------- launch ----------------

extern "C" void kernel_launch(void* const* d_in, const int* in_sizes, int n_in,
                              void* d_out, int out_size, void* d_ws, size_t ws_size,
                              hipStream_t stream) {
    const float* x   = (const float*)d_in[0];
    const int*   ei  = (const int*)d_in[1];
    const int*   bat = (const int*)d_in[2];
    const float* W1  = (const float*)d_in[3];
    const float* g1  = (const float*)d_in[5];
    const float* bt1 = (const float*)d_in[6];
    const float* Wc  = (const float*)d_in[7];
    const float* gc  = (const float*)d_in[9];
    const float* btc = (const float*)d_in[10];
    const float* Wl1 = (const float*)d_in[11];
    const float* bl1 = (const float*)d_in[12];
    const float* gl  = (const float*)d_in[13];
    const float* btl = (const float*)d_in[14];
    const float* Wl2 = (const float*)d_in[15];
    const float* bl2 = (const float*)d_in[16];
    float* out = (float*)d_out;

    const int n = in_sizes[2];
    const int e = in_sizes[1] / 2;
    const int* src = ei;
    const int* dst = ei + e;
    const int nbuck = (n + 511) / 512;  // <= 256
    const float inv_n = 1.0f / (float)n;

    size_t off = 0;
    char* base = (char*)d_ws;
    auto take = [&](size_t nbytes) -> void* {
        void* p = base + off;
        off += (nbytes + 255) & ~(size_t)255;
        return p;
    };
    int*    rp      = (int*)take((size_t)(NN + 1) * 4);
    float*  dinv    = (float*)take((size_t)NN * 4);
    // contiguous zero-init region: bhist, bcursor, stats, zst (one memset)
    int*    bhist   = (int*)take(1024);
    int*    bcursor = (int*)take(1024);
    float*  stats   = (float*)take(3 * 1024);
    float*  zst     = (float*)take(1024);
    uint*   ebuf    = (uint*)take((size_t)NE * 4);
    uint*   erec    = (uint*)take((size_t)NE * 4);
    int*    gptr    = (int*)take((size_t)(GG + 1) * 4);
    ushort* WTb     = (ushort*)take((size_t)3 * H * H * 2);
    ushort* hwb     = (ushort*)take((size_t)NN * H * 2);
    ushort* aggb    = (ushort*)take((size_t)3 * NN * H * 2);
    float*  pooled  = (float*)take((size_t)GG * LH * 4);
    float*  z       = (float*)take((size_t)GG * H * 4);

    // ---- single zero-init (bhist + bcursor + stats + zst, contiguous) ----
    hipMemsetAsync(bhist, 0, 1024 + 1024 + 3 * 1024 + 1024, stream);

    // ---- fused weight transpose + bucket histogram ----
    k_wt_bhist<<<448, 256, 0, stream>>>(W1, Wc, WTb, dst, bhist, e, nbuck);

    // ---- bucketed CSR build (bucket bases recomputed in-block) ----
    k_bin<<<(e + 4095) / 4096, 256, 0, stream>>>(src, dst, bhist, bcursor, ebuf, e);
    k_bfinalA<<<nbuck, 256, 0, stream>>>(ebuf, bhist, rp, dinv, n, e);
    k_bfinalB<<<nbuck, 256, 0, stream>>>(ebuf, bhist, rp, dinv, erec, n);

    // ---- 3 GCN layers (BN+ReLU of layer l-1 fused into layer l's GEMM) ----
    for (int l = 0; l < 3; ++l) {
        const ushort* WT = WTb + (size_t)l * H * H;

        if (l == 0) {
            k_gemm<0><<<(n + 63) / 64, 256, 0, stream>>>(
                x, WT, nullptr, nullptr, nullptr, inv_n, hwb, n);
        } else {
            const float* gm  = (l == 1) ? g1 : gc;
            const float* btm = (l == 1) ? bt1 : btc;
            k_gemm<1><<<(n + 63) / 64, 256, 0, stream>>>(
                aggb + (size_t)(l - 1) * NN * H, WT, stats + (size_t)(l - 1) * 256,
                gm, btm, inv_n, hwb, n);
        }
        k_agg<<<((n + 255) / 256) * 2, 256, 0, stream>>>(
            hwb, rp, erec, dinv, stats + (size_t)l * 256, aggb + (size_t)l * NN * H, n);
    }

    // ---- pooling ----
    k_gbound<<<3, 256, 0, stream>>>(bat, gptr, n);
    {
        dim3 pg(GG, 6);
        k_pool<<<pg, 256, 0, stream>>>(aggb, stats, g1, bt1, gc, btc, gptr, pooled, inv_n);
    }

    // ---- MLP head ----
    k_mlp1<<<GG, H, 0, stream>>>(pooled, Wl1, bl1, z);
    k_zstats<<<16, H, 0, stream>>>(z, zst);
    k_mlp2<<<GG, H, 0, stream>>>(z, zst, gl, btl, Wl2, bl2, out);
}